// Round 9
// baseline (99.451 us; speedup 1.0000x reference)
//
#include <hip/hip_runtime.h>

#define NPTS 2048
#define NCP  32
#define GB   4   // batches per block

// Binomial coefficients C(31, i) (exact)
static __device__ const float C31[NCP] = {
    1.f, 31.f, 465.f, 4495.f, 31465.f, 169911.f, 736281.f, 2629575.f,
    7888725.f, 20160075.f, 44352165.f, 84672315.f, 141120525.f, 206253075.f,
    265182525.f, 300540195.f, 300540195.f, 265182525.f, 206253075.f, 141120525.f,
    84672315.f, 44352165.f, 20160075.f, 7888725.f, 2629575.f, 736281.f,
    169911.f, 31465.f, 4495.f, 465.f, 31.f, 1.f
};

// Clamped knot vector value for knot index i (0..35): 4 zeros, interior
// (i-3)/29, 4 ones.
__device__ __forceinline__ float knq(int i) {
    int m = i - 3;
    m = m < 0 ? 0 : m;
    return (m >= 29) ? 1.0f : (float)m * (float)(1.0 / 29.0);
}

// Constant-address-space vector type: uniform-address loads from AS4 select
// as s_load_dwordx4 (SMEM pipe, SGPR destination) instead of ds/global.
// Must be a clang ext_vector (trivially copyable across address spaces) —
// HIP's float4 class ctor can't bind an AS4 reference (R8 compile failure).
typedef float f4 __attribute__((ext_vector_type(4)));
typedef __attribute__((address_space(4))) const f4 kf4;

// One point per thread, GB=4 batches, launch_bounds(256,8): VGPR<=64 ->
// 8 waves/SIMD (hardware max) — empirically the only regime that beats 30us.
// Bezier CPs are block-uniform -> moved off the per-CU DS pipe (70% of R2's
// DS cycles) onto the near-free scalar pipe via AS4 loads.
__global__ void __launch_bounds__(256, 8) fused_kernel(
    const float* __restrict__ bspline_cp, const float* __restrict__ nurbs_cp,
    const float* __restrict__ nurbs_w, const float* __restrict__ bezier_cp,
    float* __restrict__ out, int B) {
    const int tid = threadIdx.x;
    const int n   = blockIdx.x * 256 + tid;   // this thread's point
    const int b0  = blockIdx.y * GB;

    // Merged spline/nurbs CP array: element pair at constant 512B distance
    // (enables ds_read2_b64 fusion of the two b64 reads per k).
    __shared__ float s_cp[2][GB * NCP * 2];   // [0]=bspline, [1]=nurbs
    __shared__ float s_w [GB * NCP];
    for (int idx = tid; idx < GB * NCP * 2; idx += 256) {
        s_cp[0][idx] = bspline_cp[(size_t)b0 * NCP * 2 + idx];
        s_cp[1][idx] = nurbs_cp [(size_t)b0 * NCP * 2 + idx];
    }
    for (int idx = tid; idx < GB * NCP; idx += 256)
        s_w[idx] = nurbs_w[(size_t)b0 * NCP + idx];
    __syncthreads();

    const float t = (float)((double)n * (1.0 / (double)(NPTS - 1)));
    // Bernstein in log2 space: bern_i = C31[i] * 2^(i*(lu-lv) + 31*lv)
    const float lu = __builtin_amdgcn_logf(fmaxf(t, 1e-30f));
    const float lv = __builtin_amdgcn_logf(fmaxf(1.0f - t, 1e-30f));
    const float dd = lu - lv;
    const float e0 = 31.0f * lv;

    const unsigned cs = (unsigned)B * 2u * NPTS;   // per-curve output stride

    // ---- Cubic B-spline basis: local de Boor (4 non-zero values) ----
    int s = (int)(t * 29.0f);
    s = s < 28 ? s : 28;
    const int j = s + 3;                 // knot-span: U[j] <= t < U[j+1]
    const float L1 = t - knq(j);
    const float R1 = knq(j + 1) - t;
    const float L2 = t - knq(j - 1);
    const float R2 = knq(j + 2) - t;
    const float L3 = t - knq(j - 2);
    const float R3 = knq(j + 3) - t;
    float N0, N1, N2, N3, tmp, sv;
    tmp = __builtin_amdgcn_rcpf(R1 + L1);
    N0 = R1 * tmp;
    N1 = L1 * tmp;
    tmp = N0 * __builtin_amdgcn_rcpf(R1 + L2);
    N0 = R1 * tmp;
    sv = L2 * tmp;
    tmp = N1 * __builtin_amdgcn_rcpf(R2 + L1);
    N1 = fmaf(R2, tmp, sv);
    N2 = L1 * tmp;
    tmp = N0 * __builtin_amdgcn_rcpf(R1 + L3);
    N0 = R1 * tmp;
    sv = L3 * tmp;
    tmp = N1 * __builtin_amdgcn_rcpf(R2 + L2);
    N1 = fmaf(R2, tmp, sv);
    sv = L2 * tmp;
    tmp = N2 * __builtin_amdgcn_rcpf(R3 + L1);
    N2 = fmaf(R3, tmp, sv);
    N3 = L1 * tmp;

    // ---- B-spline + NURBS: sparse 4-term span dots (lane-varying, LDS) ----
#pragma unroll
    for (int g = 0; g < GB; ++g) {
        float sbx = 0.f, sby = 0.f, snx = 0.f, sny = 0.f, den = 0.f;
#pragma unroll
        for (int k = 0; k < 4; ++k) {
            const int idx = s + k;
            const float c = (k == 0) ? N0 : (k == 1) ? N1 : (k == 2) ? N2 : N3;
            float2 cb = *reinterpret_cast<const float2*>(&s_cp[0][g * 64 + idx * 2]);
            sbx = fmaf(c, cb.x, sbx); sby = fmaf(c, cb.y, sby);
            const float wb = c * s_w[g * 32 + idx];
            den += wb;
            float2 cn = *reinterpret_cast<const float2*>(&s_cp[1][g * 64 + idx * 2]);
            snx = fmaf(wb, cn.x, snx); sny = fmaf(wb, cn.y, sny);
        }
        const float inv = __builtin_amdgcn_rcpf(den + 1e-8f);
        const unsigned base = (unsigned)(b0 + g) * 2u * NPTS + (unsigned)n;
        out[base]             = sbx;
        out[base + NPTS]      = sby;
        out[cs + base]        = snx * inv;
        out[cs + base + NPTS] = sny * inv;
    }

    // ---- Bezier: dense 32-term dot; CPs via constant-AS scalar loads ----
    const kf4* bz4 =
        (const kf4*)(unsigned long long)(bezier_cp + (size_t)b0 * NCP * 2);
    float ex[GB], ey[GB];
#pragma unroll
    for (int g = 0; g < GB; ++g) { ex[g] = 0.f; ey[g] = 0.f; }
#pragma unroll
    for (int i = 0; i < NCP; i += 2) {
        const float ba = C31[i]     * __builtin_amdgcn_exp2f(fmaf((float)i,       dd, e0));
        const float bb = C31[i + 1] * __builtin_amdgcn_exp2f(fmaf((float)(i + 1), dd, e0));
#pragma unroll
        for (int g = 0; g < GB; ++g) {
            // uniform address (b0 + literals) in AS4 -> s_load_dwordx4;
            // c lanes are SGPRs, the one scalar operand each v_fma allows.
            // layout: (x_i, y_i, x_{i+1}, y_{i+1}) for batch g
            const f4 c = bz4[g * 16 + i / 2];
            ex[g] = fmaf(ba, c.x, fmaf(bb, c.z, ex[g]));
            ey[g] = fmaf(ba, c.y, fmaf(bb, c.w, ey[g]));
        }
    }
#pragma unroll
    for (int g = 0; g < GB; ++g) {
        const unsigned base = 2u * cs + (unsigned)(b0 + g) * 2u * NPTS + (unsigned)n;
        out[base]        = ex[g];
        out[base + NPTS] = ey[g];
    }
}

extern "C" void kernel_launch(void* const* d_in, const int* in_sizes, int n_in,
                              void* d_out, int out_size, void* d_ws, size_t ws_size,
                              hipStream_t stream) {
    const float* bspline_cp = (const float*)d_in[0];
    const float* nurbs_cp   = (const float*)d_in[1];
    const float* nurbs_w    = (const float*)d_in[2];
    const float* bezier_cp  = (const float*)d_in[3];
    float* out = (float*)d_out;

    const int B = in_sizes[2] / NCP;              // 2048

    hipLaunchKernelGGL(fused_kernel, dim3(NPTS / 256, B / GB), dim3(256), 0, stream,
                       bspline_cp, nurbs_cp, nurbs_w, bezier_cp, out, B);
}

// Round 10
// 90.787 us; speedup vs baseline: 1.0954x; 1.0954x over previous
//
#include <hip/hip_runtime.h>

#define NPTS 2048
#define NCP  32
#define P    4   // consecutive points per thread (float4 stores)
// GB = 1: one batch per block. grid 2 x 2048 = 4096 blocks -> 64 waves/CU.

// Binomial coefficients C(31, i) (exact)
static __device__ const float C31[NCP] = {
    1.f, 31.f, 465.f, 4495.f, 31465.f, 169911.f, 736281.f, 2629575.f,
    7888725.f, 20160075.f, 44352165.f, 84672315.f, 141120525.f, 206253075.f,
    265182525.f, 300540195.f, 300540195.f, 265182525.f, 206253075.f, 141120525.f,
    84672315.f, 44352165.f, 20160075.f, 7888725.f, 2629575.f, 736281.f,
    169911.f, 31465.f, 4495.f, 465.f, 31.f, 1.f
};

// Clamped knot vector value for knot index i (0..35): 4 zeros, interior
// (i-3)/29, 4 ones.
__device__ __forceinline__ float knq(int i) {
    int m = i - 3;
    m = m < 0 ? 0 : m;
    return (m >= 29) ? 1.0f : (float)m * (float)(1.0 / 29.0);
}

// DS-pipe-bound kernel (per-CU pipe -> only fewer DS instructions help).
// P=4 points x 1 batch: each wave-uniform bezier ds_read_b128 feeds 4 points
// (4/pb vs R2's 16/pb). Spline CPs interleaved {bs.x,bs.y,nc.x,nc.y} so the
// sparse inner step is 1 ds_read_b128 + 1 b32 (was 2 b64 + 1 b32).
// GB=1 keeps the live set ~50 VGPR -> launch_bounds(256,8) without spill.
__global__ void __launch_bounds__(256, 8) fused_kernel(
    const float* __restrict__ bspline_cp, const float* __restrict__ nurbs_cp,
    const float* __restrict__ nurbs_w, const float* __restrict__ bezier_cp,
    float* __restrict__ out, int B) {
    const int tid = threadIdx.x;
    const int n0  = (blockIdx.x * 256 + tid) * P;   // first of this thread's 4 points
    const int b   = blockIdx.y;                     // this block's batch

    __shared__ float4 s_cpn[NCP];        // {bs.x, bs.y, nc.x, nc.y} per CP
    __shared__ float  s_bz[NCP * 2];     // bezier (x,y) pairs
    __shared__ float  s_w [NCP];
    if (tid < 128) {                     // interleave bs/nc: 1 float/thread
        const int i = tid >> 2, c = tid & 3;
        const float* src = (c < 2) ? bspline_cp : nurbs_cp;
        reinterpret_cast<float*>(s_cpn)[tid] = src[(size_t)b * 64 + i * 2 + (c & 1)];
    } else if (tid < 192) {
        s_bz[tid - 128] = bezier_cp[(size_t)b * 64 + (tid - 128)];
    } else if (tid < 224) {
        s_w[tid - 192] = nurbs_w[(size_t)b * 32 + (tid - 192)];
    }
    __syncthreads();

    const unsigned cs = (unsigned)B * 2u * NPTS;    // per-curve output stride

    // ---- Phase B: per-p de Boor + sparse 4-term dots (streamed per p) ----
    float tt[P];
    float obx[P], oby[P], onx[P], ony[P];
#pragma unroll
    for (int p = 0; p < P; ++p) {
        const float t = (float)((double)(n0 + p) * (1.0 / (double)(NPTS - 1)));
        tt[p] = t;
        int s = (int)(t * 29.0f);
        s = s < 28 ? s : 28;
        const int j = s + 3;             // knot-span: U[j] <= t < U[j+1]
        const float L1 = t - knq(j);
        const float R1 = knq(j + 1) - t;
        const float L2 = t - knq(j - 1);
        const float R2 = knq(j + 2) - t;
        const float L3 = t - knq(j - 2);
        const float R3 = knq(j + 3) - t;
        float N0, N1, N2, N3, tmp, sv;
        tmp = __builtin_amdgcn_rcpf(R1 + L1);
        N0 = R1 * tmp;
        N1 = L1 * tmp;
        tmp = N0 * __builtin_amdgcn_rcpf(R1 + L2);
        N0 = R1 * tmp;
        sv = L2 * tmp;
        tmp = N1 * __builtin_amdgcn_rcpf(R2 + L1);
        N1 = fmaf(R2, tmp, sv);
        N2 = L1 * tmp;
        tmp = N0 * __builtin_amdgcn_rcpf(R1 + L3);
        N0 = R1 * tmp;
        sv = L3 * tmp;
        tmp = N1 * __builtin_amdgcn_rcpf(R2 + L2);
        N1 = fmaf(R2, tmp, sv);
        sv = L2 * tmp;
        tmp = N2 * __builtin_amdgcn_rcpf(R3 + L1);
        N2 = fmaf(R3, tmp, sv);
        N3 = L1 * tmp;

        float sbx = 0.f, sby = 0.f, snx = 0.f, sny = 0.f, den = 0.f;
#pragma unroll
        for (int k = 0; k < 4; ++k) {
            const int idx = s + k;
            const float c = (k == 0) ? N0 : (k == 1) ? N1 : (k == 2) ? N2 : N3;
            const float4 q = s_cpn[idx];          // 1 ds_read_b128
            sbx = fmaf(c, q.x, sbx); sby = fmaf(c, q.y, sby);
            const float wb = c * s_w[idx];        // 1 ds_read_b32
            den += wb;
            snx = fmaf(wb, q.z, snx); sny = fmaf(wb, q.w, sny);
        }
        const float inv = __builtin_amdgcn_rcpf(den + 1e-8f);
        obx[p] = sbx; oby[p] = sby;
        onx[p] = snx * inv; ony[p] = sny * inv;
    }
    {
        const unsigned base = (unsigned)b * 2u * NPTS + (unsigned)n0;
        *reinterpret_cast<float4*>(&out[base]) =
            make_float4(obx[0], obx[1], obx[2], obx[3]);
        *reinterpret_cast<float4*>(&out[base + NPTS]) =
            make_float4(oby[0], oby[1], oby[2], oby[3]);
        *reinterpret_cast<float4*>(&out[cs + base]) =
            make_float4(onx[0], onx[1], onx[2], onx[3]);
        *reinterpret_cast<float4*>(&out[cs + base + NPTS]) =
            make_float4(ony[0], ony[1], ony[2], ony[3]);
    }

    // ---- Phase C: Bezier dense 32-term dot; exp2-in-register basis ----
    float dd[P], e0[P];
#pragma unroll
    for (int p = 0; p < P; ++p) {
        const float lu = __builtin_amdgcn_logf(fmaxf(tt[p], 1e-30f));
        const float lv = __builtin_amdgcn_logf(fmaxf(1.0f - tt[p], 1e-30f));
        dd[p] = lu - lv;
        e0[p] = 31.0f * lv;
    }
    float ex[P], ey[P];
#pragma unroll
    for (int p = 0; p < P; ++p) { ex[p] = 0.f; ey[p] = 0.f; }
#pragma unroll
    for (int i = 0; i < NCP; i += 2) {
        float ba[P], bb[P];
#pragma unroll
        for (int p = 0; p < P; ++p) {
            ba[p] = C31[i]     * __builtin_amdgcn_exp2f(fmaf((float)i,       dd[p], e0[p]));
            bb[p] = C31[i + 1] * __builtin_amdgcn_exp2f(fmaf((float)(i + 1), dd[p], e0[p]));
        }
        // wave-uniform broadcast b128: (x_i, y_i, x_{i+1}, y_{i+1})
        const float4 c = *reinterpret_cast<const float4*>(&s_bz[2 * i]);
#pragma unroll
        for (int p = 0; p < P; ++p) {
            ex[p] = fmaf(ba[p], c.x, fmaf(bb[p], c.z, ex[p]));
            ey[p] = fmaf(ba[p], c.y, fmaf(bb[p], c.w, ey[p]));
        }
    }
    {
        const unsigned base = 2u * cs + (unsigned)b * 2u * NPTS + (unsigned)n0;
        *reinterpret_cast<float4*>(&out[base]) =
            make_float4(ex[0], ex[1], ex[2], ex[3]);
        *reinterpret_cast<float4*>(&out[base + NPTS]) =
            make_float4(ey[0], ey[1], ey[2], ey[3]);
    }
}

extern "C" void kernel_launch(void* const* d_in, const int* in_sizes, int n_in,
                              void* d_out, int out_size, void* d_ws, size_t ws_size,
                              hipStream_t stream) {
    const float* bspline_cp = (const float*)d_in[0];
    const float* nurbs_cp   = (const float*)d_in[1];
    const float* nurbs_w    = (const float*)d_in[2];
    const float* bezier_cp  = (const float*)d_in[3];
    float* out = (float*)d_out;

    const int B = in_sizes[2] / NCP;              // 2048

    hipLaunchKernelGGL(fused_kernel, dim3(NPTS / (256 * P), B), dim3(256), 0, stream,
                       bspline_cp, nurbs_cp, nurbs_w, bezier_cp, out, B);
}